// Round 9
// baseline (215.863 us; speedup 1.0000x reference)
//
#include <hip/hip_runtime.h>
#include <math.h>

#define B_  8
#define N_  1024
#define H_  512
#define NH_ 8
#define DK_ 64
#define M_  (B_ * N_)   // 8192

typedef __attribute__((ext_vector_type(4))) float f32x4;
typedef __attribute__((ext_vector_type(8))) short bf16x8;

__device__ __forceinline__ unsigned short f2bf(float f) {
    unsigned int u = __float_as_uint(f);
    u = (u + 0x7fffu + ((u >> 16) & 1u)) >> 16;   // RNE
    return (unsigned short)u;
}

__device__ __forceinline__ float bf2f(unsigned short s) {
    return __uint_as_float(((unsigned int)s) << 16);
}

__device__ __forceinline__ float fexp2(float x) {
#if __has_builtin(__builtin_amdgcn_exp2f)
    return __builtin_amdgcn_exp2f(x);
#else
    return exp2f(x);
#endif
}

__device__ __forceinline__ void gload16(const unsigned short* g, unsigned short* l) {
    __builtin_amdgcn_global_load_lds(
        (const __attribute__((address_space(1))) void*)g,
        (__attribute__((address_space(3))) void*)l, 16, 0, 0);
}

// ---------------------------------------------------------------------------
// prep: fp32->bf16 convert of x / Wq (pre-scaled by 0.125*log2e) / Wk/Wv/Wg.
// Segments (blocks): x 4096 | Wq 256 | Wk 256 | Wv 256 | Wg 512.
// ---------------------------------------------------------------------------
__global__ __launch_bounds__(256) void prep_k(const float* __restrict__ x,
                                              const float* __restrict__ Wq,
                                              const float* __restrict__ Wk,
                                              const float* __restrict__ Wv,
                                              const float* __restrict__ Wg,
                                              unsigned short* __restrict__ xb,
                                              unsigned short* __restrict__ wqb,
                                              unsigned short* __restrict__ wkb,
                                              unsigned short* __restrict__ wvb,
                                              unsigned short* __restrict__ wgb)
{
    int id = blockIdx.x;
    const float* src; unsigned short* dst; int off; float scale = 1.0f;
    if (id < 4096)      { src = x;  dst = xb;  off = id; }
    else if (id < 4352) { src = Wq; dst = wqb; off = id - 4096; scale = 0.18033688011112042f; } // 0.125*log2(e)
    else if (id < 4608) { src = Wk; dst = wkb; off = id - 4352; }
    else if (id < 4864) { src = Wv; dst = wvb; off = id - 4608; }
    else                { src = Wg; dst = wgb; off = id - 4864; }
    size_t i = (size_t)off * 1024 + threadIdx.x * 4;
    float4 v = *(const float4*)&src[i];
    *(ushort4*)&dst[i] = make_ushort4(f2bf(v.x * scale), f2bf(v.y * scale),
                                      f2bf(v.z * scale), f2bf(v.w * scale));
}

// ---------------------------------------------------------------------------
// Fused launch: adj bitmask pack (blocks 0..2047, memory-pipe, 0 LDS — they
// co-reside with proj blocks and fill latency bubbles per the m114
// MFMA/VALU co-schedule) + QKV projection (blocks 2048..2815).
// proj: BK=32 double-buffered pipelined, 128x128 tile, 4 waves 2x2.
// w=0 -> qk[:,0:512], w=1 -> qk[:,512:1024], w=2 -> Vt (transposed store).
// ---------------------------------------------------------------------------
__global__ __launch_bounds__(256, 3) void proj_k(const unsigned short* __restrict__ xb,
                                                 const unsigned short* __restrict__ Wqb,
                                                 const unsigned short* __restrict__ Wkb,
                                                 const unsigned short* __restrict__ Wvb,
                                                 const int* __restrict__ adj,
                                                 unsigned short* __restrict__ qk,
                                                 unsigned short* __restrict__ vt,
                                                 unsigned long long* __restrict__ mb)
{
    const int bid = blockIdx.x;
    if (bid < 2048) {                    // ---- pack: 4 adj rows per block ----
        int wv   = threadIdx.x >> 6;
        int lane = threadIdx.x & 63;
        int row  = bid * 4 + wv;         // b*N + q
        const int* arow = &adj[(size_t)row * N_];
        #pragma unroll
        for (int kt = 0; kt < 16; ++kt) {
            unsigned long long m = __ballot(arow[kt * 64 + lane] != 0);
            if (lane == 0) mb[(size_t)row * 16 + kt] = m;
        }
        return;
    }

    __shared__ unsigned short As[2][4096];   // [c4:0..3][row:0..127] chunks, 8 KB each
    __shared__ unsigned short Bs[2][4096];
    const int pb = bid - 2048;
    const int tid = threadIdx.x;
    const int lane = tid & 63, wv = tid >> 6;
    const int ln = lane & 15, quad = lane >> 4;
    const int wm = wv >> 1, wn = wv & 1;
    const int row0 = (pb & 63) * 128;
    const int by   = pb >> 6;                // 0..11
    const int w    = by >> 2;
    const int col0 = (by & 3) * 128;
    const unsigned short* W = (w == 0) ? Wqb : ((w == 1) ? Wkb : Wvb);
    f32x4 acc[4][4] = {};

    auto issue = [&](int t, int bi) {
        int kt = t * 32;
        #pragma unroll
        for (int i = 0; i < 2; ++i) {
            int c = tid + i * 256;          // 0..511
            int c4 = c >> 7, row = c & 127;
            gload16(&xb[(size_t)(row0 + row) * H_ + kt + c4 * 8], &As[bi][c * 8]);
            gload16(&W [(size_t)(col0 + row) * H_ + kt + c4 * 8], &Bs[bi][c * 8]);
        }
    };

    issue(0, 0);
    for (int t = 0; t < 16; ++t) {
        __syncthreads();                     // buffer t&1 ready
        if (t < 15) issue(t + 1, (t + 1) & 1);
        const unsigned short* Ac = As[t & 1];
        const unsigned short* Bc = Bs[t & 1];
        bf16x8 af[4], bf[4];
        #pragma unroll
        for (int u = 0; u < 4; ++u) {
            af[u] = *(const bf16x8*)&Ac[(quad * 128 + wm * 64 + u * 16 + ln) * 8];
            bf[u] = *(const bf16x8*)&Bc[(quad * 128 + wn * 64 + u * 16 + ln) * 8];
        }
        #pragma unroll
        for (int mt = 0; mt < 4; ++mt)
            #pragma unroll
            for (int nt = 0; nt < 4; ++nt)
                acc[mt][nt] = __builtin_amdgcn_mfma_f32_16x16x32_bf16(af[mt], bf[nt], acc[mt][nt], 0, 0, 0);
    }

    if (w < 2) {
        #pragma unroll
        for (int mt = 0; mt < 4; ++mt)
            #pragma unroll
            for (int nt = 0; nt < 4; ++nt)
                #pragma unroll
                for (int r = 0; r < 4; ++r) {
                    int m = row0 + wm * 64 + mt * 16 + quad * 4 + r;
                    int c = w * H_ + col0 + wn * 64 + nt * 16 + ln;
                    qk[(size_t)m * (2 * H_) + c] = f2bf(acc[mt][nt][r]);
                }
    } else {
        // V: store transposed -> vt[((b*NH+head)*DK + d)*N + n], n = m % N
        #pragma unroll
        for (int mt = 0; mt < 4; ++mt)
            #pragma unroll
            for (int nt = 0; nt < 4; ++nt) {
                int c = col0 + wn * 64 + nt * 16 + ln;   // 0..511
                int head = c >> 6, d = c & 63;
                int m0 = row0 + wm * 64 + mt * 16 + quad * 4;
                int bb = m0 >> 10, n = m0 & (N_ - 1);
                ushort4 u = make_ushort4(f2bf(acc[mt][nt][0]), f2bf(acc[mt][nt][1]),
                                         f2bf(acc[mt][nt][2]), f2bf(acc[mt][nt][3]));
                *(ushort4*)&vt[((size_t)(bb * NH_ + head) * DK_ + d) * N_ + n] = u;
            }
    }
}

// ---------------------------------------------------------------------------
// Flash attention, S^T formulation, 128 q per block (2 groups of 16 per
// wave), double-buffered K/V staging with pipelined global_load_lds.
// XCD-locality swizzle: bh = blockIdx.x & 63 (fastest) -> all q-tiles of a
// (b,head) land on one XCD; per-XCD K/V working set = 2 MB < 4 MB L2.
// exp2 softmax, no max subtraction (Q pre-scaled by 0.125*log2e).
// ---------------------------------------------------------------------------
__global__ __launch_bounds__(256, 3) void attn_k(const unsigned short* __restrict__ qk,
                                                 const unsigned short* __restrict__ Vt,
                                                 const unsigned long long* __restrict__ Mb,
                                                 unsigned short* __restrict__ Cmb)
{
    const int bh   = blockIdx.x & 63;            // same head group -> same XCD
    const int qt   = blockIdx.x >> 6;            // 0..7
    const int b    = bh >> 3;
    const int head = bh & 7;

    __shared__ unsigned short Ks[2][4096];       // [c8:0..7][row:0..63] chunks
    __shared__ unsigned short Vs[2][4096];
    __shared__ unsigned short Ps[4][2][16][72];  // per-wave, per-group: [q=ln][key]

    const int tid = threadIdx.x;
    const int lane = tid & 63, wv = tid >> 6;
    const int ln = lane & 15, quad = lane >> 4;
    const int q0 = qt * 128 + wv * 32 + ln;
    const int q1 = q0 + 16;

    const unsigned short* Kbase = qk + H_ + head * DK_;
    const unsigned short* Vbase = Vt + (size_t)(b * NH_ + head) * DK_ * N_;

    bf16x8 bq[2][2];
    #pragma unroll
    for (int kk = 0; kk < 2; ++kk) {
        bq[0][kk] = *(const bf16x8*)&qk[(size_t)(b * N_ + q0) * (2 * H_) + head * DK_ + kk * 32 + quad * 8];
        bq[1][kk] = *(const bf16x8*)&qk[(size_t)(b * N_ + q1) * (2 * H_) + head * DK_ + kk * 32 + quad * 8];
    }

    f32x4 o[2][4] = {};
    float psum[2] = {0.f, 0.f};

    auto issue = [&](int t, int bi) {
        #pragma unroll
        for (int i = 0; i < 2; ++i) {
            int c = tid + i * 256;               // 0..511
            int c8 = c >> 6, row = c & 63;
            gload16(&Kbase[(size_t)(b * N_ + t * 64 + row) * (2 * H_) + c8 * 8], &Ks[bi][c * 8]);
            gload16(&Vbase[(size_t)row * N_ + t * 64 + c8 * 8], &Vs[bi][c * 8]);
        }
    };

    issue(0, 0);

    for (int t = 0; t < 16; ++t) {
        __syncthreads();                         // tile t visible
        if (t < 15) issue(t + 1, (t + 1) & 1);
        const unsigned short* Kc = Ks[t & 1];
        const unsigned short* Vc = Vs[t & 1];

        unsigned long long mq[2];
        mq[0] = Mb[(size_t)(b * N_ + q0) * 16 + t];
        mq[1] = Mb[(size_t)(b * N_ + q1) * 16 + t];

        // S^T strips for both q-groups; shared K fragments
        f32x4 s[2][4] = {};
        #pragma unroll
        for (int kk = 0; kk < 2; ++kk)
            #pragma unroll
            for (int nt = 0; nt < 4; ++nt) {
                bf16x8 ka = *(const bf16x8*)&Kc[((kk * 4 + quad) * 64 + nt * 16 + ln) * 8];
                s[0][nt] = __builtin_amdgcn_mfma_f32_16x16x32_bf16(ka, bq[0][kk], s[0][nt], 0, 0, 0);
                s[1][nt] = __builtin_amdgcn_mfma_f32_16x16x32_bf16(ka, bq[1][kk], s[1][nt], 0, 0, 0);
            }

        // p = mask ? exp2(s) : 0; pack to bf16 into per-wave LDS
        #pragma unroll
        for (int g = 0; g < 2; ++g) {
            unsigned long long sh = mq[g] >> (quad * 4);
            #pragma unroll
            for (int nt = 0; nt < 4; ++nt) {
                unsigned int bn = (unsigned int)(sh >> (nt * 16)) & 0xFu;
                float p[4];
                #pragma unroll
                for (int r = 0; r < 4; ++r) {
                    float e = fexp2(s[g][nt][r]);
                    p[r] = (bn & (1u << r)) ? e : 0.f;
                    psum[g] += p[r];
                }
                unsigned int d0 = __builtin_amdgcn_perm(__float_as_uint(p[1]), __float_as_uint(p[0]), 0x07060302u);
                unsigned int d1 = __builtin_amdgcn_perm(__float_as_uint(p[3]), __float_as_uint(p[2]), 0x07060302u);
                *(uint2*)&Ps[wv][g][ln][nt * 16 + quad * 4] = make_uint2(d0, d1);
            }
        }

        bf16x8 pb[2][2];
        #pragma unroll
        for (int g = 0; g < 2; ++g)
            #pragma unroll
            for (int kk = 0; kk < 2; ++kk)
                pb[g][kk] = *(const bf16x8*)&Ps[wv][g][ln][kk * 32 + quad * 8];

        // O^T += V^T P^T; shared V fragments
        #pragma unroll
        for (int kk = 0; kk < 2; ++kk)
            #pragma unroll
            for (int dt = 0; dt < 4; ++dt) {
                bf16x8 va = *(const bf16x8*)&Vc[((kk * 4 + quad) * 64 + dt * 16 + ln) * 8];
                o[0][dt] = __builtin_amdgcn_mfma_f32_16x16x32_bf16(va, pb[0][kk], o[0][dt], 0, 0, 0);
                o[1][dt] = __builtin_amdgcn_mfma_f32_16x16x32_bf16(va, pb[1][kk], o[1][dt], 0, 0, 0);
            }
    }

    #pragma unroll
    for (int g = 0; g < 2; ++g) {
        psum[g] += __shfl_xor(psum[g], 16);
        psum[g] += __shfl_xor(psum[g], 32);
        float inv = 1.f / psum[g];
        int qg = (g == 0) ? q0 : q1;
        #pragma unroll
        for (int dt = 0; dt < 4; ++dt) {
            ushort4 u = make_ushort4(f2bf(o[g][dt][0] * inv), f2bf(o[g][dt][1] * inv),
                                     f2bf(o[g][dt][2] * inv), f2bf(o[g][dt][3] * inv));
            *(ushort4*)&Cmb[(size_t)(b * N_ + qg) * H_ + head * DK_ + dt * 16 + quad * 4] = u;
        }
    }
}

// ---------------------------------------------------------------------------
// Gate GEMM (K=1024, A=[cmb|xb] bf16), BK=32 double-buffered pipelined,
// + sigmoid + residual (bf16 x), fp32 out. 128x64 tile. grid (64,8).
// ---------------------------------------------------------------------------
__global__ __launch_bounds__(256, 3) void gate_k(const unsigned short* __restrict__ cmb,
                                                 const unsigned short* __restrict__ xb,
                                                 const unsigned short* __restrict__ Wgb,
                                                 const float* __restrict__ bgp,
                                                 float* __restrict__ out)
{
    __shared__ unsigned short As[2][4096];   // [c4:0..3][row:0..127], 8 KB each
    __shared__ unsigned short Bs[2][2048];   // [c4:0..3][row:0..63],  4 KB each
    const int tid = threadIdx.x;
    const int lane = tid & 63, wv = tid >> 6;
    const int ln = lane & 15, quad = lane >> 4;
    const int wm = wv >> 1, wn = wv & 1;
    const int row0 = blockIdx.x * 128;
    const int col0 = blockIdx.y * 64;
    f32x4 acc[4][2] = {};

    auto issue = [&](int t, int bi) {
        const unsigned short* Asrc = (t < 16) ? cmb : xb;
        int ko = (t * 32) & (H_ - 1);
        #pragma unroll
        for (int i = 0; i < 2; ++i) {
            int c = tid + i * 256;            // 0..511
            int c4 = c >> 7, row = c & 127;
            gload16(&Asrc[(size_t)(row0 + row) * H_ + ko + c4 * 8], &As[bi][c * 8]);
        }
        {
            int c = tid & 255;                // 0..255
            int c4 = c >> 6, row = c & 63;
            if (tid < 256)
                gload16(&Wgb[(size_t)(col0 + row) * (2 * H_) + t * 32 + c4 * 8], &Bs[bi][c * 8]);
        }
    };

    issue(0, 0);
    for (int t = 0; t < 32; ++t) {
        __syncthreads();
        if (t < 31) issue(t + 1, (t + 1) & 1);
        const unsigned short* Ac = As[t & 1];
        const unsigned short* Bc = Bs[t & 1];
        bf16x8 af[4], bf[2];
        #pragma unroll
        for (int u = 0; u < 4; ++u)
            af[u] = *(const bf16x8*)&Ac[(quad * 128 + wm * 64 + u * 16 + ln) * 8];
        #pragma unroll
        for (int u = 0; u < 2; ++u)
            bf[u] = *(const bf16x8*)&Bc[(quad * 64 + wn * 32 + u * 16 + ln) * 8];
        #pragma unroll
        for (int mt = 0; mt < 4; ++mt)
            #pragma unroll
            for (int nt = 0; nt < 2; ++nt)
                acc[mt][nt] = __builtin_amdgcn_mfma_f32_16x16x32_bf16(af[mt], bf[nt], acc[mt][nt], 0, 0, 0);
    }

    #pragma unroll
    for (int mt = 0; mt < 4; ++mt)
        #pragma unroll
        for (int nt = 0; nt < 2; ++nt)
            #pragma unroll
            for (int r = 0; r < 4; ++r) {
                int m = row0 + wm * 64 + mt * 16 + quad * 4 + r;
                int c = col0 + wn * 32 + nt * 16 + ln;
                float g  = 1.f / (1.f + __expf(-(acc[mt][nt][r] + bgp[c])));
                float xv = bf2f(xb[(size_t)m * H_ + c]);
                float cv = bf2f(cmb[(size_t)m * H_ + c]);
                out[(size_t)m * H_ + c] = g * xv + (1.f - g) * cv;
            }
}

// ---------------------------------------------------------------------------
extern "C" void kernel_launch(void* const* d_in, const int* in_sizes, int n_in,
                              void* d_out, int out_size, void* d_ws, size_t ws_size,
                              hipStream_t stream)
{
    const float* x   = (const float*)d_in[0];
    const int*   adj = (const int*)  d_in[1];
    const float* Wq  = (const float*)d_in[2];
    const float* Wk  = (const float*)d_in[3];
    const float* Wv  = (const float*)d_in[4];
    const float* Wg  = (const float*)d_in[5];
    const float* bg  = (const float*)d_in[6];
    float* out = (float*)d_out;

    unsigned short* xb  = (unsigned short*)d_ws;                      // 8 MB
    unsigned short* wqb = xb  + (size_t)M_ * H_;                      // 512 KB
    unsigned short* wkb = wqb + (size_t)H_ * H_;
    unsigned short* wvb = wkb + (size_t)H_ * H_;
    unsigned short* wgb = wvb + (size_t)H_ * H_;                      // 1 MB
    unsigned short* qk  = wgb + (size_t)H_ * 2 * H_;                  // 16 MB
    unsigned short* vt  = qk  + (size_t)M_ * 2 * H_;                  // 8 MB
    unsigned short* cmb = vt  + (size_t)M_ * H_;                      // 8 MB
    unsigned long long* mb = (unsigned long long*)(cmb + (size_t)M_ * H_);  // 1 MB

    prep_k<<<5376, 256, 0, stream>>>(x, Wq, Wk, Wv, Wg, xb, wqb, wkb, wvb, wgb);

    proj_k<<<2048 + 768, 256, 0, stream>>>(xb, wqb, wkb, wvb, adj, qk, vt, mb);

    attn_k<<<B_ * NH_ * (N_ / 128), 256, 0, stream>>>(qk, vt, mb, cmb);

    gate_k<<<dim3(M_ / 128, H_ / 64), 256, 0, stream>>>(cmb, xb, wgb, bg, out);
}

// Round 10
// 202.197 us; speedup vs baseline: 1.0676x; 1.0676x over previous
//
#include <hip/hip_runtime.h>
#include <math.h>

#define B_  8
#define N_  1024
#define H_  512
#define NH_ 8
#define DK_ 64
#define M_  (B_ * N_)   // 8192

typedef __attribute__((ext_vector_type(4))) float f32x4;
typedef __attribute__((ext_vector_type(8))) short bf16x8;

__device__ __forceinline__ unsigned short f2bf(float f) {
    unsigned int u = __float_as_uint(f);
    u = (u + 0x7fffu + ((u >> 16) & 1u)) >> 16;   // RNE
    return (unsigned short)u;
}

__device__ __forceinline__ float bf2f(unsigned short s) {
    return __uint_as_float(((unsigned int)s) << 16);
}

__device__ __forceinline__ float fexp2(float x) {
#if __has_builtin(__builtin_amdgcn_exp2f)
    return __builtin_amdgcn_exp2f(x);
#else
    return exp2f(x);
#endif
}

__device__ __forceinline__ void gload16(const unsigned short* g, unsigned short* l) {
    __builtin_amdgcn_global_load_lds(
        (const __attribute__((address_space(1))) void*)g,
        (__attribute__((address_space(3))) void*)l, 16, 0, 0);
}

// ---------------------------------------------------------------------------
// Fused prep: fp32->bf16 convert of x/Wq(pre-scaled)/Wk/Wv/Wg  +  adj bitmask
// pack. Segments (blocks): x 4096 | Wq 256 | Wk 256 | Wv 256 | Wg 512 |
// pack 8192 (one q-row per block; wave wv does words wv*4..wv*4+3).
// (r9 showed pack must NOT lead the proj launch — dispatch order serializes.)
// ---------------------------------------------------------------------------
__global__ __launch_bounds__(256) void prep_k(const float* __restrict__ x,
                                              const float* __restrict__ Wq,
                                              const float* __restrict__ Wk,
                                              const float* __restrict__ Wv,
                                              const float* __restrict__ Wg,
                                              const int*   __restrict__ adj,
                                              unsigned short* __restrict__ xb,
                                              unsigned short* __restrict__ wqb,
                                              unsigned short* __restrict__ wkb,
                                              unsigned short* __restrict__ wvb,
                                              unsigned short* __restrict__ wgb,
                                              unsigned long long* __restrict__ mb)
{
    int id = blockIdx.x;
    if (id >= 5376) {   // pack segment: one (b,q) row per block
        int row  = id - 5376;                  // b*N + q
        int wv   = threadIdx.x >> 6;
        int lane = threadIdx.x & 63;
        const int* arow = &adj[(size_t)row * N_];
        #pragma unroll
        for (int j = 0; j < 4; ++j) {
            int kt = wv * 4 + j;
            int val = arow[kt * 64 + lane];
            unsigned long long m = __ballot(val != 0);
            if (lane == 0) mb[(size_t)row * 16 + kt] = m;
        }
        return;
    }
    const float* src; unsigned short* dst; int off; float scale = 1.0f;
    if (id < 4096)      { src = x;  dst = xb;  off = id; }
    else if (id < 4352) { src = Wq; dst = wqb; off = id - 4096; scale = 0.18033688011112042f; } // 0.125*log2(e)
    else if (id < 4608) { src = Wk; dst = wkb; off = id - 4352; }
    else if (id < 4864) { src = Wv; dst = wvb; off = id - 4608; }
    else                { src = Wg; dst = wgb; off = id - 4864; }
    size_t i = (size_t)off * 1024 + threadIdx.x * 4;
    float4 v = *(const float4*)&src[i];
    *(ushort4*)&dst[i] = make_ushort4(f2bf(v.x * scale), f2bf(v.y * scale),
                                      f2bf(v.z * scale), f2bf(v.w * scale));
}

// ---------------------------------------------------------------------------
// Fused QKV projection, BK=32 double-buffered pipelined.
// w=0 -> qk[:,0:512], w=1 -> qk[:,512:1024], w=2 -> Vt (transposed store).
// 128x128 tile, 4 waves 2x2. grid (64, 12) = 768 blocks = 3/CU.
// ---------------------------------------------------------------------------
__global__ __launch_bounds__(256, 3) void proj_k(const unsigned short* __restrict__ xb,
                                                 const unsigned short* __restrict__ Wqb,
                                                 const unsigned short* __restrict__ Wkb,
                                                 const unsigned short* __restrict__ Wvb,
                                                 unsigned short* __restrict__ qk,
                                                 unsigned short* __restrict__ vt)
{
    __shared__ unsigned short As[2][4096];   // [c4:0..3][row:0..127] chunks, 8 KB each
    __shared__ unsigned short Bs[2][4096];
    const int tid = threadIdx.x;
    const int lane = tid & 63, wv = tid >> 6;
    const int ln = lane & 15, quad = lane >> 4;
    const int wm = wv >> 1, wn = wv & 1;
    const int row0 = blockIdx.x * 128;
    const int w    = blockIdx.y >> 2;
    const int col0 = (blockIdx.y & 3) * 128;
    const unsigned short* W = (w == 0) ? Wqb : ((w == 1) ? Wkb : Wvb);
    f32x4 acc[4][4] = {};

    auto issue = [&](int t, int bi) {
        int kt = t * 32;
        #pragma unroll
        for (int i = 0; i < 2; ++i) {
            int c = tid + i * 256;          // 0..511
            int c4 = c >> 7, row = c & 127;
            gload16(&xb[(size_t)(row0 + row) * H_ + kt + c4 * 8], &As[bi][c * 8]);
            gload16(&W [(size_t)(col0 + row) * H_ + kt + c4 * 8], &Bs[bi][c * 8]);
        }
    };

    issue(0, 0);
    for (int t = 0; t < 16; ++t) {
        __syncthreads();                     // buffer t&1 ready
        if (t < 15) issue(t + 1, (t + 1) & 1);
        const unsigned short* Ac = As[t & 1];
        const unsigned short* Bc = Bs[t & 1];
        bf16x8 af[4], bf[4];
        #pragma unroll
        for (int u = 0; u < 4; ++u) {
            af[u] = *(const bf16x8*)&Ac[(quad * 128 + wm * 64 + u * 16 + ln) * 8];
            bf[u] = *(const bf16x8*)&Bc[(quad * 128 + wn * 64 + u * 16 + ln) * 8];
        }
        #pragma unroll
        for (int mt = 0; mt < 4; ++mt)
            #pragma unroll
            for (int nt = 0; nt < 4; ++nt)
                acc[mt][nt] = __builtin_amdgcn_mfma_f32_16x16x32_bf16(af[mt], bf[nt], acc[mt][nt], 0, 0, 0);
    }

    if (w < 2) {
        #pragma unroll
        for (int mt = 0; mt < 4; ++mt)
            #pragma unroll
            for (int nt = 0; nt < 4; ++nt)
                #pragma unroll
                for (int r = 0; r < 4; ++r) {
                    int m = row0 + wm * 64 + mt * 16 + quad * 4 + r;
                    int c = w * H_ + col0 + wn * 64 + nt * 16 + ln;
                    qk[(size_t)m * (2 * H_) + c] = f2bf(acc[mt][nt][r]);
                }
    } else {
        // V: store transposed -> vt[((b*NH+head)*DK + d)*N + n], n = m % N
        #pragma unroll
        for (int mt = 0; mt < 4; ++mt)
            #pragma unroll
            for (int nt = 0; nt < 4; ++nt) {
                int c = col0 + wn * 64 + nt * 16 + ln;   // 0..511
                int head = c >> 6, d = c & 63;
                int m0 = row0 + wm * 64 + mt * 16 + quad * 4;
                int bb = m0 >> 10, n = m0 & (N_ - 1);
                ushort4 u = make_ushort4(f2bf(acc[mt][nt][0]), f2bf(acc[mt][nt][1]),
                                         f2bf(acc[mt][nt][2]), f2bf(acc[mt][nt][3]));
                *(ushort4*)&vt[((size_t)(bb * NH_ + head) * DK_ + d) * N_ + n] = u;
            }
    }
}

// ---------------------------------------------------------------------------
// Flash attention, S^T formulation, 128 q per block (2 groups of 16 per
// wave), double-buffered K/V staging with pipelined global_load_lds.
// XCD-locality swizzle: bh = blockIdx.x & 63 (fastest) -> all q-tiles of a
// (b,head) land on one XCD; per-XCD K/V working set = 2 MB < 4 MB L2.
// exp2 softmax, no max subtraction (Q pre-scaled by 0.125*log2e).
// ---------------------------------------------------------------------------
__global__ __launch_bounds__(256, 3) void attn_k(const unsigned short* __restrict__ qk,
                                                 const unsigned short* __restrict__ Vt,
                                                 const unsigned long long* __restrict__ Mb,
                                                 unsigned short* __restrict__ Cmb)
{
    const int bh   = blockIdx.x & 63;            // same head group -> same XCD
    const int qt   = blockIdx.x >> 6;            // 0..7
    const int b    = bh >> 3;
    const int head = bh & 7;

    __shared__ unsigned short Ks[2][4096];       // [c8:0..7][row:0..63] chunks
    __shared__ unsigned short Vs[2][4096];
    __shared__ unsigned short Ps[4][2][16][72];  // per-wave, per-group: [q=ln][key]

    const int tid = threadIdx.x;
    const int lane = tid & 63, wv = tid >> 6;
    const int ln = lane & 15, quad = lane >> 4;
    const int q0 = qt * 128 + wv * 32 + ln;
    const int q1 = q0 + 16;

    const unsigned short* Kbase = qk + H_ + head * DK_;
    const unsigned short* Vbase = Vt + (size_t)(b * NH_ + head) * DK_ * N_;

    bf16x8 bq[2][2];
    #pragma unroll
    for (int kk = 0; kk < 2; ++kk) {
        bq[0][kk] = *(const bf16x8*)&qk[(size_t)(b * N_ + q0) * (2 * H_) + head * DK_ + kk * 32 + quad * 8];
        bq[1][kk] = *(const bf16x8*)&qk[(size_t)(b * N_ + q1) * (2 * H_) + head * DK_ + kk * 32 + quad * 8];
    }

    f32x4 o[2][4] = {};
    float psum[2] = {0.f, 0.f};

    auto issue = [&](int t, int bi) {
        #pragma unroll
        for (int i = 0; i < 2; ++i) {
            int c = tid + i * 256;               // 0..511
            int c8 = c >> 6, row = c & 63;
            gload16(&Kbase[(size_t)(b * N_ + t * 64 + row) * (2 * H_) + c8 * 8], &Ks[bi][c * 8]);
            gload16(&Vbase[(size_t)row * N_ + t * 64 + c8 * 8], &Vs[bi][c * 8]);
        }
    };

    issue(0, 0);

    for (int t = 0; t < 16; ++t) {
        __syncthreads();                         // tile t visible
        if (t < 15) issue(t + 1, (t + 1) & 1);
        const unsigned short* Kc = Ks[t & 1];
        const unsigned short* Vc = Vs[t & 1];

        unsigned long long mq[2];
        mq[0] = Mb[(size_t)(b * N_ + q0) * 16 + t];
        mq[1] = Mb[(size_t)(b * N_ + q1) * 16 + t];

        // S^T strips for both q-groups; shared K fragments
        f32x4 s[2][4] = {};
        #pragma unroll
        for (int kk = 0; kk < 2; ++kk)
            #pragma unroll
            for (int nt = 0; nt < 4; ++nt) {
                bf16x8 ka = *(const bf16x8*)&Kc[((kk * 4 + quad) * 64 + nt * 16 + ln) * 8];
                s[0][nt] = __builtin_amdgcn_mfma_f32_16x16x32_bf16(ka, bq[0][kk], s[0][nt], 0, 0, 0);
                s[1][nt] = __builtin_amdgcn_mfma_f32_16x16x32_bf16(ka, bq[1][kk], s[1][nt], 0, 0, 0);
            }

        // p = mask ? exp2(s) : 0; pack to bf16 into per-wave LDS
        #pragma unroll
        for (int g = 0; g < 2; ++g) {
            unsigned long long sh = mq[g] >> (quad * 4);
            #pragma unroll
            for (int nt = 0; nt < 4; ++nt) {
                unsigned int bn = (unsigned int)(sh >> (nt * 16)) & 0xFu;
                float p[4];
                #pragma unroll
                for (int r = 0; r < 4; ++r) {
                    float e = fexp2(s[g][nt][r]);
                    p[r] = (bn & (1u << r)) ? e : 0.f;
                    psum[g] += p[r];
                }
                unsigned int d0 = __builtin_amdgcn_perm(__float_as_uint(p[1]), __float_as_uint(p[0]), 0x07060302u);
                unsigned int d1 = __builtin_amdgcn_perm(__float_as_uint(p[3]), __float_as_uint(p[2]), 0x07060302u);
                *(uint2*)&Ps[wv][g][ln][nt * 16 + quad * 4] = make_uint2(d0, d1);
            }
        }

        bf16x8 pb[2][2];
        #pragma unroll
        for (int g = 0; g < 2; ++g)
            #pragma unroll
            for (int kk = 0; kk < 2; ++kk)
                pb[g][kk] = *(const bf16x8*)&Ps[wv][g][ln][kk * 32 + quad * 8];

        // O^T += V^T P^T; shared V fragments
        #pragma unroll
        for (int kk = 0; kk < 2; ++kk)
            #pragma unroll
            for (int dt = 0; dt < 4; ++dt) {
                bf16x8 va = *(const bf16x8*)&Vc[((kk * 4 + quad) * 64 + dt * 16 + ln) * 8];
                o[0][dt] = __builtin_amdgcn_mfma_f32_16x16x32_bf16(va, pb[0][kk], o[0][dt], 0, 0, 0);
                o[1][dt] = __builtin_amdgcn_mfma_f32_16x16x32_bf16(va, pb[1][kk], o[1][dt], 0, 0, 0);
            }
    }

    #pragma unroll
    for (int g = 0; g < 2; ++g) {
        psum[g] += __shfl_xor(psum[g], 16);
        psum[g] += __shfl_xor(psum[g], 32);
        float inv = 1.f / psum[g];
        int qg = (g == 0) ? q0 : q1;
        #pragma unroll
        for (int dt = 0; dt < 4; ++dt) {
            ushort4 u = make_ushort4(f2bf(o[g][dt][0] * inv), f2bf(o[g][dt][1] * inv),
                                     f2bf(o[g][dt][2] * inv), f2bf(o[g][dt][3] * inv));
            *(ushort4*)&Cmb[(size_t)(b * N_ + qg) * H_ + head * DK_ + dt * 16 + quad * 4] = u;
        }
    }
}

// ---------------------------------------------------------------------------
// Gate GEMM (K=1024, A=[cmb|xb] bf16), BK=64 double-buffered pipelined
// (16 MFMAs per barrier, 16 K-steps — r9 diagnosis: 8/barrier was the
// bottleneck), + sigmoid + residual (bf16 x), fp32 out. 128x64 tile,
// grid (64,8). LDS 48 KB -> 3 blocks/CU capacity.
// ---------------------------------------------------------------------------
__global__ __launch_bounds__(256, 3) void gate_k(const unsigned short* __restrict__ cmb,
                                                 const unsigned short* __restrict__ xb,
                                                 const unsigned short* __restrict__ Wgb,
                                                 const float* __restrict__ bgp,
                                                 float* __restrict__ out)
{
    __shared__ unsigned short As[2][8192];   // [c8:0..7][row:0..127], 16 KB each
    __shared__ unsigned short Bs[2][4096];   // [c8:0..7][row:0..63],   8 KB each
    const int tid = threadIdx.x;
    const int lane = tid & 63, wv = tid >> 6;
    const int ln = lane & 15, quad = lane >> 4;
    const int wm = wv >> 1, wn = wv & 1;
    const int row0 = blockIdx.x * 128;
    const int col0 = blockIdx.y * 64;
    f32x4 acc[4][2] = {};

    auto issue = [&](int t, int bi) {
        const unsigned short* Asrc = (t < 8) ? cmb : xb;
        int ko = (t * 64) & (H_ - 1);
        #pragma unroll
        for (int i = 0; i < 4; ++i) {
            int c = tid + i * 256;            // 0..1023
            int c8 = c >> 7, row = c & 127;
            gload16(&Asrc[(size_t)(row0 + row) * H_ + ko + c8 * 8], &As[bi][c * 8]);
        }
        #pragma unroll
        for (int i = 0; i < 2; ++i) {
            int c = tid + i * 256;            // 0..511
            int c8 = c >> 6, row = c & 63;
            gload16(&Wgb[(size_t)(col0 + row) * (2 * H_) + t * 64 + c8 * 8], &Bs[bi][c * 8]);
        }
    };

    issue(0, 0);
    for (int t = 0; t < 16; ++t) {
        __syncthreads();
        if (t < 15) issue(t + 1, (t + 1) & 1);
        const unsigned short* Ac = As[t & 1];
        const unsigned short* Bc = Bs[t & 1];
        #pragma unroll
        for (int kk = 0; kk < 2; ++kk) {
            bf16x8 af[4], bf[2];
            #pragma unroll
            for (int u = 0; u < 4; ++u)
                af[u] = *(const bf16x8*)&Ac[((kk * 4 + quad) * 128 + wm * 64 + u * 16 + ln) * 8];
            #pragma unroll
            for (int u = 0; u < 2; ++u)
                bf[u] = *(const bf16x8*)&Bc[((kk * 4 + quad) * 64 + wn * 32 + u * 16 + ln) * 8];
            #pragma unroll
            for (int mt = 0; mt < 4; ++mt)
                #pragma unroll
                for (int nt = 0; nt < 2; ++nt)
                    acc[mt][nt] = __builtin_amdgcn_mfma_f32_16x16x32_bf16(af[mt], bf[nt], acc[mt][nt], 0, 0, 0);
        }
    }

    #pragma unroll
    for (int mt = 0; mt < 4; ++mt)
        #pragma unroll
        for (int nt = 0; nt < 2; ++nt)
            #pragma unroll
            for (int r = 0; r < 4; ++r) {
                int m = row0 + wm * 64 + mt * 16 + quad * 4 + r;
                int c = col0 + wn * 32 + nt * 16 + ln;
                float g  = 1.f / (1.f + __expf(-(acc[mt][nt][r] + bgp[c])));
                float xv = bf2f(xb[(size_t)m * H_ + c]);
                float cv = bf2f(cmb[(size_t)m * H_ + c]);
                out[(size_t)m * H_ + c] = g * xv + (1.f - g) * cv;
            }
}

// ---------------------------------------------------------------------------
extern "C" void kernel_launch(void* const* d_in, const int* in_sizes, int n_in,
                              void* d_out, int out_size, void* d_ws, size_t ws_size,
                              hipStream_t stream)
{
    const float* x   = (const float*)d_in[0];
    const int*   adj = (const int*)  d_in[1];
    const float* Wq  = (const float*)d_in[2];
    const float* Wk  = (const float*)d_in[3];
    const float* Wv  = (const float*)d_in[4];
    const float* Wg  = (const float*)d_in[5];
    const float* bg  = (const float*)d_in[6];
    float* out = (float*)d_out;

    unsigned short* xb  = (unsigned short*)d_ws;                      // 8 MB
    unsigned short* wqb = xb  + (size_t)M_ * H_;                      // 512 KB
    unsigned short* wkb = wqb + (size_t)H_ * H_;
    unsigned short* wvb = wkb + (size_t)H_ * H_;
    unsigned short* wgb = wvb + (size_t)H_ * H_;                      // 1 MB
    unsigned short* qk  = wgb + (size_t)H_ * 2 * H_;                  // 16 MB
    unsigned short* vt  = qk  + (size_t)M_ * 2 * H_;                  // 8 MB
    unsigned short* cmb = vt  + (size_t)M_ * H_;                      // 8 MB
    unsigned long long* mb = (unsigned long long*)(cmb + (size_t)M_ * H_);  // 1 MB

    prep_k<<<5376 + 8192, 256, 0, stream>>>(x, Wq, Wk, Wv, Wg, adj,
                                            xb, wqb, wkb, wvb, wgb, mb);

    proj_k<<<dim3(M_ / 128, 12), 256, 0, stream>>>(xb, wqb, wkb, wvb, qk, vt);

    attn_k<<<B_ * NH_ * (N_ / 128), 256, 0, stream>>>(qk, vt, mb, cmb);

    gate_k<<<dim3(M_ / 128, H_ / 64), 256, 0, stream>>>(cmb, xb, wgb, bg, out);
}

// Round 11
// 201.595 us; speedup vs baseline: 1.0708x; 1.0030x over previous
//
#include <hip/hip_runtime.h>
#include <math.h>

#define B_  8
#define N_  1024
#define H_  512
#define NH_ 8
#define DK_ 64
#define M_  (B_ * N_)   // 8192

typedef __attribute__((ext_vector_type(4))) float f32x4;
typedef __attribute__((ext_vector_type(8))) short bf16x8;

__device__ __forceinline__ unsigned short f2bf(float f) {
    unsigned int u = __float_as_uint(f);
    u = (u + 0x7fffu + ((u >> 16) & 1u)) >> 16;   // RNE
    return (unsigned short)u;
}

__device__ __forceinline__ float bf2f(unsigned short s) {
    return __uint_as_float(((unsigned int)s) << 16);
}

__device__ __forceinline__ float fexp2(float x) {
#if __has_builtin(__builtin_amdgcn_exp2f)
    return __builtin_amdgcn_exp2f(x);
#else
    return exp2f(x);
#endif
}

__device__ __forceinline__ void gload16(const unsigned short* g, unsigned short* l) {
    __builtin_amdgcn_global_load_lds(
        (const __attribute__((address_space(1))) void*)g,
        (__attribute__((address_space(3))) void*)l, 16, 0, 0);
}

// ---------------------------------------------------------------------------
// Fused prep: fp32->bf16 convert of x/Wq(pre-scaled)/Wk/Wv/Wg  +  adj bitmask
// pack. Segments (blocks): x 4096 | Wq 256 | Wk 256 | Wv 256 | Wg 512 |
// pack 8192 (one q-row per block; wave wv does words wv*4..wv*4+3).
// (r9 showed pack must NOT lead the proj launch — dispatch order serializes.)
// ---------------------------------------------------------------------------
__global__ __launch_bounds__(256) void prep_k(const float* __restrict__ x,
                                              const float* __restrict__ Wq,
                                              const float* __restrict__ Wk,
                                              const float* __restrict__ Wv,
                                              const float* __restrict__ Wg,
                                              const int*   __restrict__ adj,
                                              unsigned short* __restrict__ xb,
                                              unsigned short* __restrict__ wqb,
                                              unsigned short* __restrict__ wkb,
                                              unsigned short* __restrict__ wvb,
                                              unsigned short* __restrict__ wgb,
                                              unsigned long long* __restrict__ mb)
{
    int id = blockIdx.x;
    if (id >= 5376) {   // pack segment: one (b,q) row per block
        int row  = id - 5376;                  // b*N + q
        int wv   = threadIdx.x >> 6;
        int lane = threadIdx.x & 63;
        const int* arow = &adj[(size_t)row * N_];
        #pragma unroll
        for (int j = 0; j < 4; ++j) {
            int kt = wv * 4 + j;
            int val = arow[kt * 64 + lane];
            unsigned long long m = __ballot(val != 0);
            if (lane == 0) mb[(size_t)row * 16 + kt] = m;
        }
        return;
    }
    const float* src; unsigned short* dst; int off; float scale = 1.0f;
    if (id < 4096)      { src = x;  dst = xb;  off = id; }
    else if (id < 4352) { src = Wq; dst = wqb; off = id - 4096; scale = 0.18033688011112042f; } // 0.125*log2(e)
    else if (id < 4608) { src = Wk; dst = wkb; off = id - 4352; }
    else if (id < 4864) { src = Wv; dst = wvb; off = id - 4608; }
    else                { src = Wg; dst = wgb; off = id - 4864; }
    size_t i = (size_t)off * 1024 + threadIdx.x * 4;
    float4 v = *(const float4*)&src[i];
    *(ushort4*)&dst[i] = make_ushort4(f2bf(v.x * scale), f2bf(v.y * scale),
                                      f2bf(v.z * scale), f2bf(v.w * scale));
}

// ---------------------------------------------------------------------------
// Fused QKV projection, BK=32 double-buffered pipelined.
// w=0 -> qk[:,0:512], w=1 -> qk[:,512:1024], w=2 -> Vt (transposed store).
// 128x128 tile, 4 waves 2x2. grid (64, 12) = 768 blocks = 3/CU.
// ---------------------------------------------------------------------------
__global__ __launch_bounds__(256, 3) void proj_k(const unsigned short* __restrict__ xb,
                                                 const unsigned short* __restrict__ Wqb,
                                                 const unsigned short* __restrict__ Wkb,
                                                 const unsigned short* __restrict__ Wvb,
                                                 unsigned short* __restrict__ qk,
                                                 unsigned short* __restrict__ vt)
{
    __shared__ unsigned short As[2][4096];   // [c4:0..3][row:0..127] chunks, 8 KB each
    __shared__ unsigned short Bs[2][4096];
    const int tid = threadIdx.x;
    const int lane = tid & 63, wv = tid >> 6;
    const int ln = lane & 15, quad = lane >> 4;
    const int wm = wv >> 1, wn = wv & 1;
    const int row0 = blockIdx.x * 128;
    const int w    = blockIdx.y >> 2;
    const int col0 = (blockIdx.y & 3) * 128;
    const unsigned short* W = (w == 0) ? Wqb : ((w == 1) ? Wkb : Wvb);
    f32x4 acc[4][4] = {};

    auto issue = [&](int t, int bi) {
        int kt = t * 32;
        #pragma unroll
        for (int i = 0; i < 2; ++i) {
            int c = tid + i * 256;          // 0..511
            int c4 = c >> 7, row = c & 127;
            gload16(&xb[(size_t)(row0 + row) * H_ + kt + c4 * 8], &As[bi][c * 8]);
            gload16(&W [(size_t)(col0 + row) * H_ + kt + c4 * 8], &Bs[bi][c * 8]);
        }
    };

    issue(0, 0);
    for (int t = 0; t < 16; ++t) {
        __syncthreads();                     // buffer t&1 ready
        if (t < 15) issue(t + 1, (t + 1) & 1);
        const unsigned short* Ac = As[t & 1];
        const unsigned short* Bc = Bs[t & 1];
        bf16x8 af[4], bf[4];
        #pragma unroll
        for (int u = 0; u < 4; ++u) {
            af[u] = *(const bf16x8*)&Ac[(quad * 128 + wm * 64 + u * 16 + ln) * 8];
            bf[u] = *(const bf16x8*)&Bc[(quad * 128 + wn * 64 + u * 16 + ln) * 8];
        }
        #pragma unroll
        for (int mt = 0; mt < 4; ++mt)
            #pragma unroll
            for (int nt = 0; nt < 4; ++nt)
                acc[mt][nt] = __builtin_amdgcn_mfma_f32_16x16x32_bf16(af[mt], bf[nt], acc[mt][nt], 0, 0, 0);
    }

    if (w < 2) {
        #pragma unroll
        for (int mt = 0; mt < 4; ++mt)
            #pragma unroll
            for (int nt = 0; nt < 4; ++nt)
                #pragma unroll
                for (int r = 0; r < 4; ++r) {
                    int m = row0 + wm * 64 + mt * 16 + quad * 4 + r;
                    int c = w * H_ + col0 + wn * 64 + nt * 16 + ln;
                    qk[(size_t)m * (2 * H_) + c] = f2bf(acc[mt][nt][r]);
                }
    } else {
        // V: store transposed -> vt[((b*NH+head)*DK + d)*N + n], n = m % N
        #pragma unroll
        for (int mt = 0; mt < 4; ++mt)
            #pragma unroll
            for (int nt = 0; nt < 4; ++nt) {
                int c = col0 + wn * 64 + nt * 16 + ln;   // 0..511
                int head = c >> 6, d = c & 63;
                int m0 = row0 + wm * 64 + mt * 16 + quad * 4;
                int bb = m0 >> 10, n = m0 & (N_ - 1);
                ushort4 u = make_ushort4(f2bf(acc[mt][nt][0]), f2bf(acc[mt][nt][1]),
                                         f2bf(acc[mt][nt][2]), f2bf(acc[mt][nt][3]));
                *(ushort4*)&vt[((size_t)(bb * NH_ + head) * DK_ + d) * N_ + n] = u;
            }
    }
}

// ---------------------------------------------------------------------------
// Flash attention, S^T formulation, 128 q per block (2 groups of 16 per
// wave), double-buffered K/V staging with pipelined global_load_lds.
// XCD-locality swizzle: bh = blockIdx.x & 63 fastest.
// exp2 softmax, no max subtraction (Q pre-scaled by 0.125*log2e).
// NEW (r11): psum computed via ones-MFMA (column sums of P^T accumulate in
// an extra f32x4) — deletes 32 psum adds/tile/wave + end shfl chains, and
// makes the denominator sum the same bf16 p's the PV numerator uses.
// ---------------------------------------------------------------------------
__global__ __launch_bounds__(256, 3) void attn_k(const unsigned short* __restrict__ qk,
                                                 const unsigned short* __restrict__ Vt,
                                                 const unsigned long long* __restrict__ Mb,
                                                 unsigned short* __restrict__ Cmb)
{
    const int bh   = blockIdx.x & 63;            // same head group -> same XCD
    const int qt   = blockIdx.x >> 6;            // 0..7
    const int b    = bh >> 3;
    const int head = bh & 7;

    __shared__ unsigned short Ks[2][4096];       // [c8:0..7][row:0..63] chunks
    __shared__ unsigned short Vs[2][4096];
    __shared__ unsigned short Ps[4][2][16][72];  // per-wave, per-group: [q=ln][key]

    const int tid = threadIdx.x;
    const int lane = tid & 63, wv = tid >> 6;
    const int ln = lane & 15, quad = lane >> 4;
    const int q0 = qt * 128 + wv * 32 + ln;
    const int q1 = q0 + 16;

    const unsigned short* Kbase = qk + H_ + head * DK_;
    const unsigned short* Vbase = Vt + (size_t)(b * NH_ + head) * DK_ * N_;

    bf16x8 bq[2][2];
    #pragma unroll
    for (int kk = 0; kk < 2; ++kk) {
        bq[0][kk] = *(const bf16x8*)&qk[(size_t)(b * N_ + q0) * (2 * H_) + head * DK_ + kk * 32 + quad * 8];
        bq[1][kk] = *(const bf16x8*)&qk[(size_t)(b * N_ + q1) * (2 * H_) + head * DK_ + kk * 32 + quad * 8];
    }

    // ones A-fragment (bf16 1.0 = 0x3F80) for the psum MFMA
    bf16x8 ones;
    #pragma unroll
    for (int j = 0; j < 8; ++j) ones[j] = (short)0x3F80;

    f32x4 o[2][4] = {};
    f32x4 osum[2] = {};              // psum accumulators (all C-rows identical)

    auto issue = [&](int t, int bi) {
        #pragma unroll
        for (int i = 0; i < 2; ++i) {
            int c = tid + i * 256;               // 0..511
            int c8 = c >> 6, row = c & 63;
            gload16(&Kbase[(size_t)(b * N_ + t * 64 + row) * (2 * H_) + c8 * 8], &Ks[bi][c * 8]);
            gload16(&Vbase[(size_t)row * N_ + t * 64 + c8 * 8], &Vs[bi][c * 8]);
        }
    };

    issue(0, 0);

    for (int t = 0; t < 16; ++t) {
        __syncthreads();                         // tile t visible
        if (t < 15) issue(t + 1, (t + 1) & 1);
        const unsigned short* Kc = Ks[t & 1];
        const unsigned short* Vc = Vs[t & 1];

        unsigned long long mq[2];
        mq[0] = Mb[(size_t)(b * N_ + q0) * 16 + t];
        mq[1] = Mb[(size_t)(b * N_ + q1) * 16 + t];

        // S^T strips for both q-groups; shared K fragments
        f32x4 s[2][4] = {};
        #pragma unroll
        for (int kk = 0; kk < 2; ++kk)
            #pragma unroll
            for (int nt = 0; nt < 4; ++nt) {
                bf16x8 ka = *(const bf16x8*)&Kc[((kk * 4 + quad) * 64 + nt * 16 + ln) * 8];
                s[0][nt] = __builtin_amdgcn_mfma_f32_16x16x32_bf16(ka, bq[0][kk], s[0][nt], 0, 0, 0);
                s[1][nt] = __builtin_amdgcn_mfma_f32_16x16x32_bf16(ka, bq[1][kk], s[1][nt], 0, 0, 0);
            }

        // p = mask ? exp2(s) : 0; pack to bf16 into per-wave LDS
        #pragma unroll
        for (int g = 0; g < 2; ++g) {
            unsigned long long sh = mq[g] >> (quad * 4);
            #pragma unroll
            for (int nt = 0; nt < 4; ++nt) {
                unsigned int bn = (unsigned int)(sh >> (nt * 16)) & 0xFu;
                float p[4];
                #pragma unroll
                for (int r = 0; r < 4; ++r) {
                    float e = fexp2(s[g][nt][r]);
                    p[r] = (bn & (1u << r)) ? e : 0.f;
                }
                unsigned int d0 = __builtin_amdgcn_perm(__float_as_uint(p[1]), __float_as_uint(p[0]), 0x07060302u);
                unsigned int d1 = __builtin_amdgcn_perm(__float_as_uint(p[3]), __float_as_uint(p[2]), 0x07060302u);
                *(uint2*)&Ps[wv][g][ln][nt * 16 + quad * 4] = make_uint2(d0, d1);
            }
        }

        bf16x8 pb[2][2];
        #pragma unroll
        for (int g = 0; g < 2; ++g)
            #pragma unroll
            for (int kk = 0; kk < 2; ++kk)
                pb[g][kk] = *(const bf16x8*)&Ps[wv][g][ln][kk * 32 + quad * 8];

        // O^T += V^T P^T; shared V fragments.  psum += 1^T P^T via ones-MFMA.
        #pragma unroll
        for (int kk = 0; kk < 2; ++kk) {
            #pragma unroll
            for (int dt = 0; dt < 4; ++dt) {
                bf16x8 va = *(const bf16x8*)&Vc[((kk * 4 + quad) * 64 + dt * 16 + ln) * 8];
                o[0][dt] = __builtin_amdgcn_mfma_f32_16x16x32_bf16(va, pb[0][kk], o[0][dt], 0, 0, 0);
                o[1][dt] = __builtin_amdgcn_mfma_f32_16x16x32_bf16(va, pb[1][kk], o[1][dt], 0, 0, 0);
            }
            osum[0] = __builtin_amdgcn_mfma_f32_16x16x32_bf16(ones, pb[0][kk], osum[0], 0, 0, 0);
            osum[1] = __builtin_amdgcn_mfma_f32_16x16x32_bf16(ones, pb[1][kk], osum[1], 0, 0, 0);
        }
    }

    #pragma unroll
    for (int g = 0; g < 2; ++g) {
        float inv = 1.f / osum[g][0];            // all rows identical = psum[q=ln]
        int qg = (g == 0) ? q0 : q1;
        #pragma unroll
        for (int dt = 0; dt < 4; ++dt) {
            ushort4 u = make_ushort4(f2bf(o[g][dt][0] * inv), f2bf(o[g][dt][1] * inv),
                                     f2bf(o[g][dt][2] * inv), f2bf(o[g][dt][3] * inv));
            *(ushort4*)&Cmb[(size_t)(b * N_ + qg) * H_ + head * DK_ + dt * 16 + quad * 4] = u;
        }
    }
}

// ---------------------------------------------------------------------------
// Gate GEMM (K=1024, A=[cmb|xb] bf16), BK=64 double-buffered pipelined,
// + sigmoid + residual (bf16 x), fp32 out. 128x64 tile, grid (64,8).
// ---------------------------------------------------------------------------
__global__ __launch_bounds__(256, 3) void gate_k(const unsigned short* __restrict__ cmb,
                                                 const unsigned short* __restrict__ xb,
                                                 const unsigned short* __restrict__ Wgb,
                                                 const float* __restrict__ bgp,
                                                 float* __restrict__ out)
{
    __shared__ unsigned short As[2][8192];   // [c8:0..7][row:0..127], 16 KB each
    __shared__ unsigned short Bs[2][4096];   // [c8:0..7][row:0..63],   8 KB each
    const int tid = threadIdx.x;
    const int lane = tid & 63, wv = tid >> 6;
    const int ln = lane & 15, quad = lane >> 4;
    const int wm = wv >> 1, wn = wv & 1;
    const int row0 = blockIdx.x * 128;
    const int col0 = blockIdx.y * 64;
    f32x4 acc[4][2] = {};

    auto issue = [&](int t, int bi) {
        const unsigned short* Asrc = (t < 8) ? cmb : xb;
        int ko = (t * 64) & (H_ - 1);
        #pragma unroll
        for (int i = 0; i < 4; ++i) {
            int c = tid + i * 256;            // 0..1023
            int c8 = c >> 7, row = c & 127;
            gload16(&Asrc[(size_t)(row0 + row) * H_ + ko + c8 * 8], &As[bi][c * 8]);
        }
        #pragma unroll
        for (int i = 0; i < 2; ++i) {
            int c = tid + i * 256;            // 0..511
            int c8 = c >> 6, row = c & 63;
            gload16(&Wgb[(size_t)(col0 + row) * (2 * H_) + t * 64 + c8 * 8], &Bs[bi][c * 8]);
        }
    };

    issue(0, 0);
    for (int t = 0; t < 16; ++t) {
        __syncthreads();
        if (t < 15) issue(t + 1, (t + 1) & 1);
        const unsigned short* Ac = As[t & 1];
        const unsigned short* Bc = Bs[t & 1];
        #pragma unroll
        for (int kk = 0; kk < 2; ++kk) {
            bf16x8 af[4], bf[2];
            #pragma unroll
            for (int u = 0; u < 4; ++u)
                af[u] = *(const bf16x8*)&Ac[((kk * 4 + quad) * 128 + wm * 64 + u * 16 + ln) * 8];
            #pragma unroll
            for (int u = 0; u < 2; ++u)
                bf[u] = *(const bf16x8*)&Bc[((kk * 4 + quad) * 64 + wn * 32 + u * 16 + ln) * 8];
            #pragma unroll
            for (int mt = 0; mt < 4; ++mt)
                #pragma unroll
                for (int nt = 0; nt < 2; ++nt)
                    acc[mt][nt] = __builtin_amdgcn_mfma_f32_16x16x32_bf16(af[mt], bf[nt], acc[mt][nt], 0, 0, 0);
        }
    }

    #pragma unroll
    for (int mt = 0; mt < 4; ++mt)
        #pragma unroll
        for (int nt = 0; nt < 2; ++nt)
            #pragma unroll
            for (int r = 0; r < 4; ++r) {
                int m = row0 + wm * 64 + mt * 16 + quad * 4 + r;
                int c = col0 + wn * 32 + nt * 16 + ln;
                float g  = 1.f / (1.f + __expf(-(acc[mt][nt][r] + bgp[c])));
                float xv = bf2f(xb[(size_t)m * H_ + c]);
                float cv = bf2f(cmb[(size_t)m * H_ + c]);
                out[(size_t)m * H_ + c] = g * xv + (1.f - g) * cv;
            }
}

// ---------------------------------------------------------------------------
extern "C" void kernel_launch(void* const* d_in, const int* in_sizes, int n_in,
                              void* d_out, int out_size, void* d_ws, size_t ws_size,
                              hipStream_t stream)
{
    const float* x   = (const float*)d_in[0];
    const int*   adj = (const int*)  d_in[1];
    const float* Wq  = (const float*)d_in[2];
    const float* Wk  = (const float*)d_in[3];
    const float* Wv  = (const float*)d_in[4];
    const float* Wg  = (const float*)d_in[5];
    const float* bg  = (const float*)d_in[6];
    float* out = (float*)d_out;

    unsigned short* xb  = (unsigned short*)d_ws;                      // 8 MB
    unsigned short* wqb = xb  + (size_t)M_ * H_;                      // 512 KB
    unsigned short* wkb = wqb + (size_t)H_ * H_;
    unsigned short* wvb = wkb + (size_t)H_ * H_;
    unsigned short* wgb = wvb + (size_t)H_ * H_;                      // 1 MB
    unsigned short* qk  = wgb + (size_t)H_ * 2 * H_;                  // 16 MB
    unsigned short* vt  = qk  + (size_t)M_ * 2 * H_;                  // 8 MB
    unsigned short* cmb = vt  + (size_t)M_ * H_;                      // 8 MB
    unsigned long long* mb = (unsigned long long*)(cmb + (size_t)M_ * H_);  // 1 MB

    prep_k<<<5376 + 8192, 256, 0, stream>>>(x, Wq, Wk, Wv, Wg, adj,
                                            xb, wqb, wkb, wvb, wgb, mb);

    proj_k<<<dim3(M_ / 128, 12), 256, 0, stream>>>(xb, wqb, wkb, wvb, qk, vt);

    attn_k<<<B_ * NH_ * (N_ / 128), 256, 0, stream>>>(qk, vt, mb, cmb);

    gate_k<<<dim3(M_ / 128, H_ / 64), 256, 0, stream>>>(cmb, xb, wgb, bg, out);
}

// Round 12
// 201.229 us; speedup vs baseline: 1.0727x; 1.0018x over previous
//
#include <hip/hip_runtime.h>
#include <math.h>

#define B_  8
#define N_  1024
#define H_  512
#define NH_ 8
#define DK_ 64
#define M_  (B_ * N_)   // 8192

typedef __attribute__((ext_vector_type(4))) float f32x4;
typedef __attribute__((ext_vector_type(8))) short bf16x8;

__device__ __forceinline__ unsigned short f2bf(float f) {
    unsigned int u = __float_as_uint(f);
    u = (u + 0x7fffu + ((u >> 16) & 1u)) >> 16;   // RNE
    return (unsigned short)u;
}

__device__ __forceinline__ float bf2f(unsigned short s) {
    return __uint_as_float(((unsigned int)s) << 16);
}

__device__ __forceinline__ float fexp2(float x) {
#if __has_builtin(__builtin_amdgcn_exp2f)
    return __builtin_amdgcn_exp2f(x);
#else
    return exp2f(x);
#endif
}

__device__ __forceinline__ void gload16(const unsigned short* g, unsigned short* l) {
    __builtin_amdgcn_global_load_lds(
        (const __attribute__((address_space(1))) void*)g,
        (__attribute__((address_space(3))) void*)l, 16, 0, 0);
}

// ---------------------------------------------------------------------------
// Fused prep: fp32->bf16 convert of x/Wq(pre-scaled)/Wk/Wv/Wg  +  adj bitmask
// pack. Segments (blocks): x 4096 | Wq 256 | Wk 256 | Wv 256 | Wg 512 |
// pack 8192 (one q-row per block; wave wv does words wv*4..wv*4+3).
// ---------------------------------------------------------------------------
__global__ __launch_bounds__(256) void prep_k(const float* __restrict__ x,
                                              const float* __restrict__ Wq,
                                              const float* __restrict__ Wk,
                                              const float* __restrict__ Wv,
                                              const float* __restrict__ Wg,
                                              const int*   __restrict__ adj,
                                              unsigned short* __restrict__ xb,
                                              unsigned short* __restrict__ wqb,
                                              unsigned short* __restrict__ wkb,
                                              unsigned short* __restrict__ wvb,
                                              unsigned short* __restrict__ wgb,
                                              unsigned long long* __restrict__ mb)
{
    int id = blockIdx.x;
    if (id >= 5376) {   // pack segment: one (b,q) row per block
        int row  = id - 5376;                  // b*N + q
        int wv   = threadIdx.x >> 6;
        int lane = threadIdx.x & 63;
        const int* arow = &adj[(size_t)row * N_];
        #pragma unroll
        for (int j = 0; j < 4; ++j) {
            int kt = wv * 4 + j;
            int val = arow[kt * 64 + lane];
            unsigned long long m = __ballot(val != 0);
            if (lane == 0) mb[(size_t)row * 16 + kt] = m;
        }
        return;
    }
    const float* src; unsigned short* dst; int off; float scale = 1.0f;
    if (id < 4096)      { src = x;  dst = xb;  off = id; }
    else if (id < 4352) { src = Wq; dst = wqb; off = id - 4096; scale = 0.18033688011112042f; } // 0.125*log2(e)
    else if (id < 4608) { src = Wk; dst = wkb; off = id - 4352; }
    else if (id < 4864) { src = Wv; dst = wvb; off = id - 4608; }
    else                { src = Wg; dst = wgb; off = id - 4864; }
    size_t i = (size_t)off * 1024 + threadIdx.x * 4;
    float4 v = *(const float4*)&src[i];
    *(ushort4*)&dst[i] = make_ushort4(f2bf(v.x * scale), f2bf(v.y * scale),
                                      f2bf(v.z * scale), f2bf(v.w * scale));
}

// ---------------------------------------------------------------------------
// Fused QKV projection, BK=32 double-buffered pipelined.
// w=0 -> qk[:,0:512], w=1 -> qk[:,512:1024], w=2 -> Vt via LDS-coalesced
// transpose epilogue (r12: old direct store scattered 16 lines/instr).
// 128x128 tile, 4 waves 2x2. grid (64, 12) = 768 blocks = 3/CU.
// ---------------------------------------------------------------------------
__global__ __launch_bounds__(256, 3) void proj_k(const unsigned short* __restrict__ xb,
                                                 const unsigned short* __restrict__ Wqb,
                                                 const unsigned short* __restrict__ Wkb,
                                                 const unsigned short* __restrict__ Wvb,
                                                 unsigned short* __restrict__ qk,
                                                 unsigned short* __restrict__ vt)
{
    // Carved shared buffer: K-loop uses As=SMEM[0..8191], Bs=SMEM[8192..16383]
    // (2 x 4096 shorts each); w==2 epilogue reuses it as Ts[128][136].
    __shared__ unsigned short SMEM[17408];   // 34816 B
    unsigned short* As = SMEM;               // [bi*4096 + idx]
    unsigned short* Bs = SMEM + 8192;

    const int tid = threadIdx.x;
    const int lane = tid & 63, wv = tid >> 6;
    const int ln = lane & 15, quad = lane >> 4;
    const int wm = wv >> 1, wn = wv & 1;
    const int row0 = blockIdx.x * 128;
    const int w    = blockIdx.y >> 2;
    const int col0 = (blockIdx.y & 3) * 128;
    const unsigned short* W = (w == 0) ? Wqb : ((w == 1) ? Wkb : Wvb);
    f32x4 acc[4][4] = {};

    auto issue = [&](int t, int bi) {
        int kt = t * 32;
        #pragma unroll
        for (int i = 0; i < 2; ++i) {
            int c = tid + i * 256;          // 0..511
            int c4 = c >> 7, row = c & 127;
            gload16(&xb[(size_t)(row0 + row) * H_ + kt + c4 * 8], &As[bi * 4096 + c * 8]);
            gload16(&W [(size_t)(col0 + row) * H_ + kt + c4 * 8], &Bs[bi * 4096 + c * 8]);
        }
    };

    issue(0, 0);
    for (int t = 0; t < 16; ++t) {
        __syncthreads();                     // buffer t&1 ready
        if (t < 15) issue(t + 1, (t + 1) & 1);
        const unsigned short* Ac = &As[(t & 1) * 4096];
        const unsigned short* Bc = &Bs[(t & 1) * 4096];
        bf16x8 af[4], bf[4];
        #pragma unroll
        for (int u = 0; u < 4; ++u) {
            af[u] = *(const bf16x8*)&Ac[(quad * 128 + wm * 64 + u * 16 + ln) * 8];
            bf[u] = *(const bf16x8*)&Bc[(quad * 128 + wn * 64 + u * 16 + ln) * 8];
        }
        #pragma unroll
        for (int mt = 0; mt < 4; ++mt)
            #pragma unroll
            for (int nt = 0; nt < 4; ++nt)
                acc[mt][nt] = __builtin_amdgcn_mfma_f32_16x16x32_bf16(af[mt], bf[nt], acc[mt][nt], 0, 0, 0);
    }

    if (w < 2) {
        #pragma unroll
        for (int mt = 0; mt < 4; ++mt)
            #pragma unroll
            for (int nt = 0; nt < 4; ++nt)
                #pragma unroll
                for (int r = 0; r < 4; ++r) {
                    int m = row0 + wm * 64 + mt * 16 + quad * 4 + r;
                    int c = w * H_ + col0 + wn * 64 + nt * 16 + ln;
                    qk[(size_t)m * (2 * H_) + c] = f2bf(acc[mt][nt][r]);
                }
    } else {
        // V: LDS transpose -> coalesced vt stores.
        // Ts[c_local][n_local], stride 136 shorts (272 B, 16-B aligned rows).
        __syncthreads();                     // all K-loop LDS reads done
        unsigned short* Ts = SMEM;
        #pragma unroll
        for (int mt = 0; mt < 4; ++mt)
            #pragma unroll
            for (int nt = 0; nt < 4; ++nt) {
                int c_local = wn * 64 + nt * 16 + ln;
                int n_local = wm * 64 + mt * 16 + quad * 4;
                ushort4 u = make_ushort4(f2bf(acc[mt][nt][0]), f2bf(acc[mt][nt][1]),
                                         f2bf(acc[mt][nt][2]), f2bf(acc[mt][nt][3]));
                *(ushort4*)&Ts[c_local * 136 + n_local] = u;
            }
        __syncthreads();
        const int bb = row0 >> 10, n_base = row0 & (N_ - 1);
        #pragma unroll
        for (int j = 0; j < 8; ++j) {
            int c_local = (tid >> 4) + j * 16;       // 0..127
            int nc = (tid & 15) * 8;                 // 0..120
            int cg = col0 + c_local;
            int head = cg >> 6, d = cg & 63;
            uint4 u = *(const uint4*)&Ts[c_local * 136 + nc];
            *(uint4*)&vt[((size_t)(bb * NH_ + head) * DK_ + d) * N_ + n_base + nc] = u;
        }
    }
}

// ---------------------------------------------------------------------------
// Flash attention, S^T formulation, 128 q per block (2 groups of 16 per
// wave), double-buffered K/V staging with pipelined global_load_lds.
// XCD-locality swizzle: bh = blockIdx.x & 63 fastest.
// exp2 softmax, no max subtraction (Q pre-scaled by 0.125*log2e).
// psum via ones-MFMA (denominator sums the same bf16 p's as the numerator).
// ---------------------------------------------------------------------------
__global__ __launch_bounds__(256, 3) void attn_k(const unsigned short* __restrict__ qk,
                                                 const unsigned short* __restrict__ Vt,
                                                 const unsigned long long* __restrict__ Mb,
                                                 unsigned short* __restrict__ Cmb)
{
    const int bh   = blockIdx.x & 63;            // same head group -> same XCD
    const int qt   = blockIdx.x >> 6;            // 0..7
    const int b    = bh >> 3;
    const int head = bh & 7;

    __shared__ unsigned short Ks[2][4096];       // [c8:0..7][row:0..63] chunks
    __shared__ unsigned short Vs[2][4096];
    __shared__ unsigned short Ps[4][2][16][72];  // per-wave, per-group: [q=ln][key]

    const int tid = threadIdx.x;
    const int lane = tid & 63, wv = tid >> 6;
    const int ln = lane & 15, quad = lane >> 4;
    const int q0 = qt * 128 + wv * 32 + ln;
    const int q1 = q0 + 16;

    const unsigned short* Kbase = qk + H_ + head * DK_;
    const unsigned short* Vbase = Vt + (size_t)(b * NH_ + head) * DK_ * N_;

    bf16x8 bq[2][2];
    #pragma unroll
    for (int kk = 0; kk < 2; ++kk) {
        bq[0][kk] = *(const bf16x8*)&qk[(size_t)(b * N_ + q0) * (2 * H_) + head * DK_ + kk * 32 + quad * 8];
        bq[1][kk] = *(const bf16x8*)&qk[(size_t)(b * N_ + q1) * (2 * H_) + head * DK_ + kk * 32 + quad * 8];
    }

    bf16x8 ones;
    #pragma unroll
    for (int j = 0; j < 8; ++j) ones[j] = (short)0x3F80;   // bf16 1.0

    f32x4 o[2][4] = {};
    f32x4 osum[2] = {};

    auto issue = [&](int t, int bi) {
        #pragma unroll
        for (int i = 0; i < 2; ++i) {
            int c = tid + i * 256;               // 0..511
            int c8 = c >> 6, row = c & 63;
            gload16(&Kbase[(size_t)(b * N_ + t * 64 + row) * (2 * H_) + c8 * 8], &Ks[bi][c * 8]);
            gload16(&Vbase[(size_t)row * N_ + t * 64 + c8 * 8], &Vs[bi][c * 8]);
        }
    };

    issue(0, 0);

    for (int t = 0; t < 16; ++t) {
        __syncthreads();                         // tile t visible
        if (t < 15) issue(t + 1, (t + 1) & 1);
        const unsigned short* Kc = Ks[t & 1];
        const unsigned short* Vc = Vs[t & 1];

        unsigned long long mq[2];
        mq[0] = Mb[(size_t)(b * N_ + q0) * 16 + t];
        mq[1] = Mb[(size_t)(b * N_ + q1) * 16 + t];

        f32x4 s[2][4] = {};
        #pragma unroll
        for (int kk = 0; kk < 2; ++kk)
            #pragma unroll
            for (int nt = 0; nt < 4; ++nt) {
                bf16x8 ka = *(const bf16x8*)&Kc[((kk * 4 + quad) * 64 + nt * 16 + ln) * 8];
                s[0][nt] = __builtin_amdgcn_mfma_f32_16x16x32_bf16(ka, bq[0][kk], s[0][nt], 0, 0, 0);
                s[1][nt] = __builtin_amdgcn_mfma_f32_16x16x32_bf16(ka, bq[1][kk], s[1][nt], 0, 0, 0);
            }

        #pragma unroll
        for (int g = 0; g < 2; ++g) {
            unsigned long long sh = mq[g] >> (quad * 4);
            #pragma unroll
            for (int nt = 0; nt < 4; ++nt) {
                unsigned int bn = (unsigned int)(sh >> (nt * 16)) & 0xFu;
                float p[4];
                #pragma unroll
                for (int r = 0; r < 4; ++r) {
                    float e = fexp2(s[g][nt][r]);
                    p[r] = (bn & (1u << r)) ? e : 0.f;
                }
                unsigned int d0 = __builtin_amdgcn_perm(__float_as_uint(p[1]), __float_as_uint(p[0]), 0x07060302u);
                unsigned int d1 = __builtin_amdgcn_perm(__float_as_uint(p[3]), __float_as_uint(p[2]), 0x07060302u);
                *(uint2*)&Ps[wv][g][ln][nt * 16 + quad * 4] = make_uint2(d0, d1);
            }
        }

        bf16x8 pb[2][2];
        #pragma unroll
        for (int g = 0; g < 2; ++g)
            #pragma unroll
            for (int kk = 0; kk < 2; ++kk)
                pb[g][kk] = *(const bf16x8*)&Ps[wv][g][ln][kk * 32 + quad * 8];

        #pragma unroll
        for (int kk = 0; kk < 2; ++kk) {
            #pragma unroll
            for (int dt = 0; dt < 4; ++dt) {
                bf16x8 va = *(const bf16x8*)&Vc[((kk * 4 + quad) * 64 + dt * 16 + ln) * 8];
                o[0][dt] = __builtin_amdgcn_mfma_f32_16x16x32_bf16(va, pb[0][kk], o[0][dt], 0, 0, 0);
                o[1][dt] = __builtin_amdgcn_mfma_f32_16x16x32_bf16(va, pb[1][kk], o[1][dt], 0, 0, 0);
            }
            osum[0] = __builtin_amdgcn_mfma_f32_16x16x32_bf16(ones, pb[0][kk], osum[0], 0, 0, 0);
            osum[1] = __builtin_amdgcn_mfma_f32_16x16x32_bf16(ones, pb[1][kk], osum[1], 0, 0, 0);
        }
    }

    #pragma unroll
    for (int g = 0; g < 2; ++g) {
        float inv = 1.f / osum[g][0];
        int qg = (g == 0) ? q0 : q1;
        #pragma unroll
        for (int dt = 0; dt < 4; ++dt) {
            ushort4 u = make_ushort4(f2bf(o[g][dt][0] * inv), f2bf(o[g][dt][1] * inv),
                                     f2bf(o[g][dt][2] * inv), f2bf(o[g][dt][3] * inv));
            *(ushort4*)&Cmb[(size_t)(b * N_ + qg) * H_ + head * DK_ + dt * 16 + quad * 4] = u;
        }
    }
}

// ---------------------------------------------------------------------------
// Gate GEMM (K=1024, A=[cmb|xb] bf16), BK=64 double-buffered pipelined,
// + sigmoid + residual (bf16 x), fp32 out. 128x64 tile, grid (64,8).
// ---------------------------------------------------------------------------
__global__ __launch_bounds__(256, 3) void gate_k(const unsigned short* __restrict__ cmb,
                                                 const unsigned short* __restrict__ xb,
                                                 const unsigned short* __restrict__ Wgb,
                                                 const float* __restrict__ bgp,
                                                 float* __restrict__ out)
{
    __shared__ unsigned short As[2][8192];   // [c8:0..7][row:0..127], 16 KB each
    __shared__ unsigned short Bs[2][4096];   // [c8:0..7][row:0..63],   8 KB each
    const int tid = threadIdx.x;
    const int lane = tid & 63, wv = tid >> 6;
    const int ln = lane & 15, quad = lane >> 4;
    const int wm = wv >> 1, wn = wv & 1;
    const int row0 = blockIdx.x * 128;
    const int col0 = blockIdx.y * 64;
    f32x4 acc[4][2] = {};

    auto issue = [&](int t, int bi) {
        const unsigned short* Asrc = (t < 8) ? cmb : xb;
        int ko = (t * 64) & (H_ - 1);
        #pragma unroll
        for (int i = 0; i < 4; ++i) {
            int c = tid + i * 256;            // 0..1023
            int c8 = c >> 7, row = c & 127;
            gload16(&Asrc[(size_t)(row0 + row) * H_ + ko + c8 * 8], &As[bi][c * 8]);
        }
        #pragma unroll
        for (int i = 0; i < 2; ++i) {
            int c = tid + i * 256;            // 0..511
            int c8 = c >> 6, row = c & 63;
            gload16(&Wgb[(size_t)(col0 + row) * (2 * H_) + t * 64 + c8 * 8], &Bs[bi][c * 8]);
        }
    };

    issue(0, 0);
    for (int t = 0; t < 16; ++t) {
        __syncthreads();
        if (t < 15) issue(t + 1, (t + 1) & 1);
        const unsigned short* Ac = As[t & 1];
        const unsigned short* Bc = Bs[t & 1];
        #pragma unroll
        for (int kk = 0; kk < 2; ++kk) {
            bf16x8 af[4], bf[2];
            #pragma unroll
            for (int u = 0; u < 4; ++u)
                af[u] = *(const bf16x8*)&Ac[((kk * 4 + quad) * 128 + wm * 64 + u * 16 + ln) * 8];
            #pragma unroll
            for (int u = 0; u < 2; ++u)
                bf[u] = *(const bf16x8*)&Bc[((kk * 4 + quad) * 64 + wn * 32 + u * 16 + ln) * 8];
            #pragma unroll
            for (int mt = 0; mt < 4; ++mt)
                #pragma unroll
                for (int nt = 0; nt < 2; ++nt)
                    acc[mt][nt] = __builtin_amdgcn_mfma_f32_16x16x32_bf16(af[mt], bf[nt], acc[mt][nt], 0, 0, 0);
        }
    }

    #pragma unroll
    for (int mt = 0; mt < 4; ++mt)
        #pragma unroll
        for (int nt = 0; nt < 2; ++nt)
            #pragma unroll
            for (int r = 0; r < 4; ++r) {
                int m = row0 + wm * 64 + mt * 16 + quad * 4 + r;
                int c = col0 + wn * 32 + nt * 16 + ln;
                float g  = 1.f / (1.f + __expf(-(acc[mt][nt][r] + bgp[c])));
                float xv = bf2f(xb[(size_t)m * H_ + c]);
                float cv = bf2f(cmb[(size_t)m * H_ + c]);
                out[(size_t)m * H_ + c] = g * xv + (1.f - g) * cv;
            }
}

// ---------------------------------------------------------------------------
extern "C" void kernel_launch(void* const* d_in, const int* in_sizes, int n_in,
                              void* d_out, int out_size, void* d_ws, size_t ws_size,
                              hipStream_t stream)
{
    const float* x   = (const float*)d_in[0];
    const int*   adj = (const int*)  d_in[1];
    const float* Wq  = (const float*)d_in[2];
    const float* Wk  = (const float*)d_in[3];
    const float* Wv  = (const float*)d_in[4];
    const float* Wg  = (const float*)d_in[5];
    const float* bg  = (const float*)d_in[6];
    float* out = (float*)d_out;

    unsigned short* xb  = (unsigned short*)d_ws;                      // 8 MB
    unsigned short* wqb = xb  + (size_t)M_ * H_;                      // 512 KB
    unsigned short* wkb = wqb + (size_t)H_ * H_;
    unsigned short* wvb = wkb + (size_t)H_ * H_;
    unsigned short* wgb = wvb + (size_t)H_ * H_;                      // 1 MB
    unsigned short* qk  = wgb + (size_t)H_ * 2 * H_;                  // 16 MB
    unsigned short* vt  = qk  + (size_t)M_ * 2 * H_;                  // 8 MB
    unsigned short* cmb = vt  + (size_t)M_ * H_;                      // 8 MB
    unsigned long long* mb = (unsigned long long*)(cmb + (size_t)M_ * H_);  // 1 MB

    prep_k<<<5376 + 8192, 256, 0, stream>>>(x, Wq, Wk, Wv, Wg, adj,
                                            xb, wqb, wkb, wvb, wgb, mb);

    proj_k<<<dim3(M_ / 128, 12), 256, 0, stream>>>(xb, wqb, wkb, wvb, qk, vt);

    attn_k<<<B_ * NH_ * (N_ / 128), 256, 0, stream>>>(qk, vt, mb, cmb);

    gate_k<<<dim3(M_ / 128, H_ / 64), 256, 0, stream>>>(cmb, xb, wgb, bg, out);
}